// Round 3
// baseline (276.167 us; speedup 1.0000x reference)
//
#include <hip/hip_runtime.h>
#include <math.h>

#define ALPHA 50.0f
#define EPS 1e-12f

constexpr int N = 64, C = 128, P = 4096, K = 64;
constexpr int NCH2 = 16;          // strips (one per block per n)

typedef short short8_t __attribute__((ext_vector_type(8)));
typedef short short4_t __attribute__((ext_vector_type(4)));
typedef float f4 __attribute__((ext_vector_type(4)));
typedef unsigned int u32x4 __attribute__((ext_vector_type(4)));
typedef unsigned int u32x2 __attribute__((ext_vector_type(2)));

__device__ __forceinline__ unsigned short f2bf(float f) {
    union { float f; unsigned u; } v; v.f = f;
    unsigned r = (v.u + 0x7FFFu + ((v.u >> 16) & 1u)) >> 16;   // RNE
    return (unsigned short)r;
}

// packed f32x2 -> bf16x2 (RNE), single VALU op
__device__ __forceinline__ unsigned cvtpk(float lo, float hi) {
    unsigned r;
    asm("v_cvt_pk_bf16_f32 %0, %1, %2" : "=v"(r) : "v"(lo), "v"(hi));
    return r;
}

// __syncthreads() minus the vmcnt(0) drain: LDS-visibility barrier only.
// Safe: all cross-thread data flows through LDS; global loads land in
// private VGPRs and global stores are only read by later kernel dispatches.
__device__ __forceinline__ void bar_lds() {
    asm volatile("s_waitcnt lgkmcnt(0)" ::: "memory");
    __builtin_amdgcn_s_barrier();
}

// ---------------------------------------------------------------------------
// Fused: per block = (n, 256-px strip) in 4 chunks of 64 px.
// LDS = 51,968 B -> 3 blocks/CU (was 69,632 -> 2/CU). Grid 1024 blocks.
// Overlays: saf==xsT (disjoint lifetimes), ssq-scratch==denom, no wnl, no
// rfin (per-wave shfl broadcast). 5 raw barriers per chunk.
// ---------------------------------------------------------------------------
__global__ __launch_bounds__(256, 3) void k_fused(
    const float* __restrict__ x, const float* __restrict__ W,
    const float* __restrict__ bias, float* __restrict__ logits,
    float* __restrict__ vlad_part, float* __restrict__ Spart,
    float* __restrict__ ss2acc)
{
    __shared__ __align__(16) char smem[51968];
    unsigned short* xsT  = (unsigned short*)smem;            // [64][136] sh, 17408 B
    unsigned short* xsN  = (unsigned short*)(smem + 17408);  // [128][76] sh, 19456 B
    float*          saf  = (float*)smem;                     // [64][68] f32 (overlays xsT)
    unsigned short* sa2s = (unsigned short*)(smem + 36864);  // [64][72] sh, 9216 B
    float*          denom= (float*)(smem + 46080);           // [16][68] f32 / ssq scratch, 4352 B
    float*          invs = (float*)(smem + 50432);           // 64 f
    float*          biass= (float*)(smem + 50688);           // 64 f
    float*          red  = (float*)(smem + 50944);           // 256 f -> ends 51968
    float*          Wl   = (float*)smem;                     // prologue: [128][68] f32 = 34816 B

    const int tid  = threadIdx.x;
    const int n    = blockIdx.x >> 4;
    const int blk16= blockIdx.x & 15;
    const int pbase = blk16 * 256;

    const int w = tid >> 6, lane = tid & 63;
    const int q = lane >> 4, l15 = lane & 15;
    const int pxg = tid & 15, cg = tid >> 4;   // staging roles

    if (blockIdx.x == 0 && tid < 64) ss2acc[tid] = 0.f;  // k_post1 accumulator
    if (tid < K) biass[tid] = bias[tid] * ALPHA;

    const float* xrow = x + (size_t)n * C * P + pbase + 4 * pxg;
    float4 va[8], vb[8];
    short8_t af[4];

    // ---- prologue: column-normalized W fragments straight from Wl ----
    {
        float4 wv[8];
        #pragma unroll
        for (int it = 0; it < 8; ++it)
            wv[it] = *(const float4*)&W[(size_t)(tid + it * 256) * 4];
        #pragma unroll
        for (int j = 0; j < 8; ++j)
            va[j] = *(const float4*)&xrow[(size_t)(8 * cg + j) * P];
        #pragma unroll
        for (int it = 0; it < 8; ++it) {
            const int idx4 = tid + it * 256;          // float4 index into W[C][K]
            *(float4*)&Wl[(idx4 >> 4) * 68 + (idx4 & 15) * 4] = wv[it];
        }
        bar_lds();
        {   // column sum-of-squares: 64 k x 4 c-parts (order-identical to prev rounds)
            const int k = tid & 63, part = tid >> 6;
            float s = 0.f;
            #pragma unroll
            for (int i = 0; i < 32; ++i) {
                float v = Wl[(part * 32 + i) * 68 + k];
                s = fmaf(v, v, s);
            }
            red[tid] = s;
        }
        bar_lds();
        if (tid < 64)
            invs[tid] = 1.0f / fmaxf(
                sqrtf(red[tid] + red[64 + tid] + red[128 + tid] + red[192 + tid]), EPS);
        bar_lds();
        {   // af[c0][j] = bf16(Wl[c][k] * cinv[k]), k = 16w + l15
            const float cv = invs[16 * w + l15];
            #pragma unroll
            for (int c0 = 0; c0 < 4; ++c0)
                #pragma unroll
                for (int j = 0; j < 8; ++j)
                    af[c0][j] = (short)f2bf(
                        Wl[(c0 * 32 + 8 * q + j) * 68 + 16 * w + l15] * cv);
        }
        // loop-top bar_lds drains these reads before staging overwrites Wl
    }

    f4 acc2[8];
    #pragma unroll
    for (int ct = 0; ct < 8; ++ct) acc2[ct] = (f4){0.f, 0.f, 0.f, 0.f};
    float Sreg = 0.f;

    const int pbT8 = 8 * (cg ^ (pxg & 7));   // write-side xsT block swizzle
    const int l4 = l15 >> 2;                 // read-side swizzle component

    for (int ch = 0; ch < 4; ++ch) {
        // ---- prefetch chunk ch+1 (stays in flight across raw barriers) ----
        if (ch < 3) {
            const float* xb = xrow + (ch + 1) * 64;
            #pragma unroll
            for (int j = 0; j < 8; ++j)
                vb[j] = *(const float4*)&xb[(size_t)(8 * cg + j) * P];
        }
        bar_lds();                           // LDS reuse guard vs prev chunk
        const int p0 = pbase + ch * 64;
        const float* vf = (const float*)va;

        // ---- sum-of-squares partials (scratch overlays denom region) ----
        float pss[4] = {0.f, 0.f, 0.f, 0.f};
        #pragma unroll
        for (int j = 0; j < 8; ++j)
            #pragma unroll
            for (int i = 0; i < 4; ++i)
                pss[i] = fmaf(vf[j * 4 + i], vf[j * 4 + i], pss[i]);
        float* rd2 = denom;                  // overlay (denom dead here)
        #pragma unroll
        for (int i = 0; i < 4; ++i) rd2[(4 * pxg + i) * 17 + cg] = pss[i];

        // ---- bf16 staging ----
        #pragma unroll
        for (int i = 0; i < 4; ++i) {        // xsT: px-row, swizzled 16B block
            u32x4 t;
            #pragma unroll
            for (int jj = 0; jj < 4; ++jj)
                t[jj] = cvtpk(vf[(2 * jj) * 4 + i], vf[(2 * jj + 1) * 4 + i]);
            *(u32x4*)&xsT[(4 * pxg + i) * 136 + pbT8] = t;
        }
        #pragma unroll
        for (int j = 0; j < 8; ++j) {        // xsN: c-row, 4 contiguous px
            u32x2 t2;
            t2[0] = cvtpk(vf[j * 4 + 0], vf[j * 4 + 1]);
            t2[1] = cvtpk(vf[j * 4 + 2], vf[j * 4 + 3]);
            *(u32x2*)&xsN[(8 * cg + j) * 76 + 4 * pxg] = t2;
        }
        bar_lds();

        // ---- invs (wave 0) overlapped with GEMM1 (all waves) ----
        if (tid < 64) {
            float s = 0.f;
            #pragma unroll
            for (int g = 0; g < 16; ++g) s += rd2[tid * 17 + g];
            invs[tid] = 1.0f / fmaxf(sqrtf(s), EPS);
        }
        f4 acc1[4];
        #pragma unroll
        for (int t = 0; t < 4; ++t) acc1[t] = (f4){0.f, 0.f, 0.f, 0.f};
        __builtin_amdgcn_s_setprio(1);
        #pragma unroll
        for (int c0 = 0; c0 < 4; ++c0)
            #pragma unroll
            for (int pxt = 0; pxt < 4; ++pxt) {
                const int pb = (4 * c0 + q) ^ (4 * (pxt & 1) + l4);
                short8_t bf = *(const short8_t*)&xsT[(pxt * 16 + l15) * 136 + pb * 8];
                acc1[pxt] = __builtin_amdgcn_mfma_f32_16x16x32_bf16(af[c0], bf, acc1[pxt], 0, 0, 0);
            }
        __builtin_amdgcn_s_setprio(0);
        bar_lds();                           // xsT dead from here: saf takes over

        // ---- logits -> global (NT), exp -> saf (over xsT), denom partials ----
        float* lgp = logits + (size_t)n * K * P + p0;
        float bz[4];
        #pragma unroll
        for (int r = 0; r < 4; ++r) bz[r] = biass[16 * w + 4 * q + r];
        #pragma unroll
        for (int pxt = 0; pxt < 4; ++pxt) {
            const int pxl = pxt * 16 + l15;
            const float iv = invs[pxl];
            float psum = 0.f;
            #pragma unroll
            for (int r = 0; r < 4; ++r) {
                const int k = 16 * w + 4 * q + r;
                const float lv = acc1[pxt][r] * iv;
                __builtin_nontemporal_store(lv, &lgp[(size_t)k * P + pxl]);
                const float e = __expf(fmaf(lv, ALPHA, bz[r]));
                saf[k * 68 + pxl] = e;
                psum += e;
            }
            denom[(4 * w + q) * 68 + pxl] = psum;
        }
        bar_lds();

        // ---- S + sa2 fused; rfin per-wave via shfl (no barrier, no LDS) ----
        {
            float dinv = 0.f;
            if (lane < 16) {
                const int pxr = 16 * w + lane;
                float dd = 0.f;
                #pragma unroll
                for (int g = 0; g < 16; ++g) dd += denom[g * 68 + pxr];
                dinv = 1.0f / dd;
            }
            const float* sp = &saf[lane * 68 + 16 * w];
            const float* ip = &invs[16 * w];
            float s = 0.f;
            unsigned pk[8];
            #pragma unroll
            for (int m = 0; m < 4; ++m) {
                f4 e  = *(const f4*)&sp[4 * m];
                f4 iv = *(const f4*)&ip[4 * m];
                const float r0 = __shfl(dinv, 4 * m + 0);
                const float r1 = __shfl(dinv, 4 * m + 1);
                const float r2 = __shfl(dinv, 4 * m + 2);
                const float r3 = __shfl(dinv, 4 * m + 3);
                s += e[0] * r0; s += e[1] * r1;
                s += e[2] * r2; s += e[3] * r3;
                const float v0 = e[0] * (r0 * iv[0]);
                const float v1 = e[1] * (r1 * iv[1]);
                const float v2 = e[2] * (r2 * iv[2]);
                const float v3 = e[3] * (r3 * iv[3]);
                pk[2 * m]     = cvtpk(v0, v1);
                pk[2 * m + 1] = cvtpk(v2, v3);
            }
            Sreg += s;
            *(u32x4*)&sa2s[lane * 72 + 16 * w]     = (u32x4){pk[0], pk[1], pk[2], pk[3]};
            *(u32x4*)&sa2s[lane * 72 + 16 * w + 8] = (u32x4){pk[4], pk[5], pk[6], pk[7]};
        }
        bar_lds();

        // ---- GEMM2: acc2[k][c] += sa2 . x_raw ----
        short8_t a2[2];
        #pragma unroll
        for (int kit = 0; kit < 2; ++kit)
            a2[kit] = *(const short8_t*)&sa2s[(16 * w + l15) * 72 + kit * 32 + 8 * q];
        __builtin_amdgcn_s_setprio(1);
        #pragma unroll
        for (int ct = 0; ct < 8; ++ct)
            #pragma unroll
            for (int kit = 0; kit < 2; ++kit) {
                const unsigned short* bp = &xsN[(ct * 16 + l15) * 76 + kit * 32 + 8 * q];
                short4_t b0 = *(const short4_t*)bp;
                short4_t b1 = *(const short4_t*)(bp + 4);
                short8_t bb;
                bb[0] = b0[0]; bb[1] = b0[1]; bb[2] = b0[2]; bb[3] = b0[3];
                bb[4] = b1[0]; bb[5] = b1[1]; bb[6] = b1[2]; bb[7] = b1[3];
                acc2[ct] = __builtin_amdgcn_mfma_f32_16x16x32_bf16(a2[kit], bb, acc2[ct], 0, 0, 0);
            }
        __builtin_amdgcn_s_setprio(0);

        if (ch < 3) {
            #pragma unroll
            for (int j = 0; j < 8; ++j) va[j] = vb[j];
        }
    }

    // ---- epilogue: per-block partials (no atomics) ----
    float* vp = vlad_part + ((size_t)blk16 * N + n) * (size_t)(K * C);
    #pragma unroll
    for (int ct = 0; ct < 8; ++ct)
        #pragma unroll
        for (int r = 0; r < 4; ++r)
            vp[(16 * w + 4 * q + r) * C + ct * 16 + l15] = acc2[ct][r];

    red[tid] = Sreg;
    __syncthreads();
    if (tid < 64)
        Spart[((size_t)blk16 * N + n) * K + tid] =
            red[tid] + red[64 + tid] + red[128 + tid] + red[192 + tid];
}

// ---------------------------------------------------------------------------
// Post 1: reduce 16 partials, subtract W*S, intra-norm (c), write un-scaled
// rows; accumulate global-norm ss2 per n via one atomic per block.
// ---------------------------------------------------------------------------
__global__ __launch_bounds__(256) void k_post1(
    const float* __restrict__ vlad_part, const float* __restrict__ W,
    const float* __restrict__ Spart, float* __restrict__ out,
    float* __restrict__ ss2acc)
{
    __shared__ float red[16];
    const int tid = threadIdx.x;
    const int n  = blockIdx.x >> 2;
    const int kq = blockIdx.x & 3;
    const int kl = tid >> 4;           // 0..15
    const int ci = tid & 15;           // 0..15
    const int k  = kq * 16 + kl;
    const int c0 = ci * 8;

    float Sk = 0.f;
    #pragma unroll
    for (int ch = 0; ch < NCH2; ++ch) Sk += Spart[(size_t)(ch * N + n) * K + k];

    float v[8];
    #pragma unroll
    for (int l = 0; l < 8; ++l) v[l] = 0.f;
    #pragma unroll
    for (int ch = 0; ch < NCH2; ++ch) {
        const float* vp = vlad_part + ((size_t)(ch * N + n) * K + k) * C + c0;
        float4 a = *(const float4*)&vp[0];
        float4 b = *(const float4*)&vp[4];
        v[0] += a.x; v[1] += a.y; v[2] += a.z; v[3] += a.w;
        v[4] += b.x; v[5] += b.y; v[6] += b.z; v[7] += b.w;
    }

    float ss = 0.f;
    #pragma unroll
    for (int l = 0; l < 8; ++l) {
        float val = v[l] - W[(size_t)(c0 + l) * K + k] * Sk;
        v[l] = val;
        ss = fmaf(val, val, ss);
    }
    ss += __shfl_xor(ss, 1);
    ss += __shfl_xor(ss, 2);
    ss += __shfl_xor(ss, 4);
    ss += __shfl_xor(ss, 8);
    const float inv1 = 1.0f / fmaxf(sqrtf(ss), EPS);
    float ss2 = 0.f;
    #pragma unroll
    for (int l = 0; l < 8; ++l) { v[l] *= inv1; ss2 = fmaf(v[l], v[l], ss2); }
    ss2 += __shfl_xor(ss2, 1);
    ss2 += __shfl_xor(ss2, 2);
    ss2 += __shfl_xor(ss2, 4);
    ss2 += __shfl_xor(ss2, 8);
    if (ci == 0) red[kl] = ss2;
    __syncthreads();
    if (tid == 0) {
        float t = 0.f;
        #pragma unroll
        for (int i = 0; i < 16; ++i) t += red[i];
        atomicAdd(&ss2acc[n], t);
    }

    float* op = out + (size_t)n * K * C + (size_t)k * C + c0;
    *(float4*)&op[0] = (float4){v[0], v[1], v[2], v[3]};
    *(float4*)&op[4] = (float4){v[4], v[5], v[6], v[7]};
}

// ---------------------------------------------------------------------------
// Post 2: global L2 rescale in place. grid = N*4.
// ---------------------------------------------------------------------------
__global__ __launch_bounds__(256) void k_post2(
    float* __restrict__ out, const float* __restrict__ ss2acc)
{
    const int n   = blockIdx.x >> 2;
    const int seg = blockIdx.x & 3;
    const float inv2 = 1.0f / fmaxf(sqrtf(ss2acc[n]), EPS);
    float* p = out + (size_t)n * K * C + (size_t)seg * 2048 + (size_t)threadIdx.x * 8;
    float4 a = *(const float4*)&p[0];
    float4 b = *(const float4*)&p[4];
    a.x *= inv2; a.y *= inv2; a.z *= inv2; a.w *= inv2;
    b.x *= inv2; b.y *= inv2; b.z *= inv2; b.w *= inv2;
    *(float4*)&p[0] = a;
    *(float4*)&p[4] = b;
}

// ---------------------------------------------------------------------------
extern "C" void kernel_launch(void* const* d_in, const int* in_sizes, int n_in,
                              void* d_out, int out_size, void* d_ws, size_t ws_size,
                              hipStream_t stream)
{
    const float* x    = (const float*)d_in[0];
    const float* W    = (const float*)d_in[1];
    const float* bias = (const float*)d_in[2];

    float* out_vlad   = (float*)d_out;                       // N*K*C
    float* out_logits = (float*)d_out + (size_t)N * K * C;   // N*K*P

    float* ss2acc     = (float*)((char*)d_ws + 16384);                  // 256 B
    float* Spart      = (float*)((char*)d_ws + 32768);                  // 256 KiB
    float* vlad_part  = (float*)((char*)d_ws + 32768 + 262144);         // 32 MiB

    k_fused<<<dim3(N * NCH2), dim3(256), 0, stream>>>(
        x, W, bias, out_logits, vlad_part, Spart, ss2acc);
    k_post1<<<dim3(N * 4), dim3(256), 0, stream>>>(vlad_part, W, Spart, out_vlad, ss2acc);
    k_post2<<<dim3(N * 4), dim3(256), 0, stream>>>(out_vlad, ss2acc);
}

// Round 4
// 235.858 us; speedup vs baseline: 1.1709x; 1.1709x over previous
//
#include <hip/hip_runtime.h>
#include <math.h>

#define ALPHA 50.0f
#define EPS 1e-12f

constexpr int N = 64, C = 128, P = 4096, K = 64;
constexpr int NCH2 = 8;           // partial groups (one per block per n)

typedef short short8_t __attribute__((ext_vector_type(8)));
typedef short short4_t __attribute__((ext_vector_type(4)));
typedef float f4 __attribute__((ext_vector_type(4)));
typedef unsigned int u32x4 __attribute__((ext_vector_type(4)));
typedef unsigned int u32x2 __attribute__((ext_vector_type(2)));

__device__ __forceinline__ unsigned short f2bf(float f) {
    union { float f; unsigned u; } v; v.f = f;
    unsigned r = (v.u + 0x7FFFu + ((v.u >> 16) & 1u)) >> 16;   // RNE
    return (unsigned short)r;
}

// packed f32x2 -> bf16x2 (RNE), single VALU op
__device__ __forceinline__ unsigned cvtpk(float lo, float hi) {
    unsigned r;
    asm("v_cvt_pk_bf16_f32 %0, %1, %2" : "=v"(r) : "v"(lo), "v"(hi));
    return r;
}

// __syncthreads() minus the vmcnt(0) drain: LDS-visibility barrier only.
// Safe: all cross-thread data flows through LDS; global loads land in
// private VGPRs and global stores are only read by later kernel dispatches.
__device__ __forceinline__ void bar_lds() {
    asm volatile("s_waitcnt lgkmcnt(0)" ::: "memory");
    __builtin_amdgcn_s_barrier();
}

// ---------------------------------------------------------------------------
// Fused: per block = (n, 512-px strip) in 8 chunks of 64 px.
// Software-pipelined: GEMM2(ch-1) overlaps staging(ch) in one phase
// (xsN double-buffered). 4 raw barriers per chunk (was 5):
//   P1: vb-issue | GEMM2(ch-1) | staging(ch)            [B1]
//   P2: invs (wave0) | GEMM1(ch)                        [B2]
//   P3: logits->global(NT), exp->saf(over xsT), denom   [B3]
//   P4: S + sa2 (shfl rfin)                             [B4]
// LDS 71,424 B -> 2 blocks/CU, grid 512 all-resident.
// ---------------------------------------------------------------------------
__global__ __launch_bounds__(256, 2) void k_fused(
    const float* __restrict__ x, const float* __restrict__ W,
    const float* __restrict__ bias, float* __restrict__ logits,
    float* __restrict__ vlad_part, float* __restrict__ Spart,
    float* __restrict__ ss2acc)
{
    __shared__ __align__(16) char smem[71424];
    unsigned short* xsT  = (unsigned short*)smem;            // [64][136] sh, 17408 B
    float*          saf  = (float*)smem;                     // [64][68] f32 (overlays xsT)
    // xsN double buffer: smem+17408 + 19456*buf, each [128][76] sh
    unsigned short* sa2s = (unsigned short*)(smem + 56320);  // [64][72] sh, 9216 B
    float*          denom= (float*)(smem + 65536);           // [16][68] f32 / ssq scratch, 4352 B
    float*          invs = (float*)(smem + 69888);           // 64 f
    float*          biass= (float*)(smem + 70144);           // 64 f
    float*          red  = (float*)(smem + 70400);           // 256 f -> ends 71424
    float*          Wl   = (float*)smem;                     // prologue: [128][68] f32 = 34816 B

    const int tid  = threadIdx.x;
    const int n    = blockIdx.x >> 3;
    const int blk8 = blockIdx.x & 7;
    const int pbase = blk8 * 512;

    const int w = tid >> 6, lane = tid & 63;
    const int q = lane >> 4, l15 = lane & 15;
    const int pxg = tid & 15, cg = tid >> 4;   // staging roles

    if (blockIdx.x == 0 && tid < 64) ss2acc[tid] = 0.f;  // k_post1 accumulator
    if (tid < K) biass[tid] = bias[tid] * ALPHA;

    const float* xrow = x + (size_t)n * C * P + pbase + 4 * pxg;
    float4 va[8], vb[8];
    short8_t af[4];

    // ---- prologue: column-normalized W fragments straight from Wl ----
    {
        float4 wv[8];
        #pragma unroll
        for (int it = 0; it < 8; ++it)
            wv[it] = *(const float4*)&W[(size_t)(tid + it * 256) * 4];
        #pragma unroll
        for (int j = 0; j < 8; ++j)
            va[j] = *(const float4*)&xrow[(size_t)(8 * cg + j) * P];
        #pragma unroll
        for (int it = 0; it < 8; ++it) {
            const int idx4 = tid + it * 256;          // float4 index into W[C][K]
            *(float4*)&Wl[(idx4 >> 4) * 68 + (idx4 & 15) * 4] = wv[it];
        }
        bar_lds();
        {   // column sum-of-squares: 64 k x 4 c-parts (order-identical)
            const int k = tid & 63, part = tid >> 6;
            float s = 0.f;
            #pragma unroll
            for (int i = 0; i < 32; ++i) {
                float v = Wl[(part * 32 + i) * 68 + k];
                s = fmaf(v, v, s);
            }
            red[tid] = s;
        }
        bar_lds();
        if (tid < 64)
            invs[tid] = 1.0f / fmaxf(
                sqrtf(red[tid] + red[64 + tid] + red[128 + tid] + red[192 + tid]), EPS);
        bar_lds();
        {   // af[c0][j] = bf16(Wl[c][k] * cinv[k]), k = 16w + l15
            const float cv = invs[16 * w + l15];
            #pragma unroll
            for (int c0 = 0; c0 < 4; ++c0)
                #pragma unroll
                for (int j = 0; j < 8; ++j)
                    af[c0][j] = (short)f2bf(
                        Wl[(c0 * 32 + 8 * q + j) * 68 + 16 * w + l15] * cv);
        }
        bar_lds();   // af reads drained before staging(0) overwrites Wl
    }

    f4 acc2[8];
    #pragma unroll
    for (int ct = 0; ct < 8; ++ct) acc2[ct] = (f4){0.f, 0.f, 0.f, 0.f};
    float Sreg = 0.f;

    const int pbT8 = 8 * (cg ^ (pxg & 7));   // write-side xsT block swizzle
    const int l4 = l15 >> 2;                 // read-side swizzle component

    for (int ch = 0; ch < 8; ++ch) {
        // ================= P1: vb-issue | GEMM2(ch-1) | staging(ch) ========
        if (ch < 7) {
            const float* xb = xrow + (ch + 1) * 64;
            #pragma unroll
            for (int j = 0; j < 8; ++j)
                vb[j] = *(const float4*)&xb[(size_t)(8 * cg + j) * P];
        }
        if (ch > 0) {   // GEMM2(ch-1): acc2[k][c] += sa2 . x_raw (prev buf)
            const unsigned short* xsNr =
                (const unsigned short*)(smem + 17408 + 19456 * ((ch - 1) & 1));
            short8_t a2[2];
            #pragma unroll
            for (int kit = 0; kit < 2; ++kit)
                a2[kit] = *(const short8_t*)&sa2s[(16 * w + l15) * 72 + kit * 32 + 8 * q];
            __builtin_amdgcn_s_setprio(1);
            #pragma unroll
            for (int ct = 0; ct < 8; ++ct)
                #pragma unroll
                for (int kit = 0; kit < 2; ++kit) {
                    const unsigned short* bp = &xsNr[(ct * 16 + l15) * 76 + kit * 32 + 8 * q];
                    short4_t b0 = *(const short4_t*)bp;
                    short4_t b1 = *(const short4_t*)(bp + 4);
                    short8_t bb;
                    bb[0] = b0[0]; bb[1] = b0[1]; bb[2] = b0[2]; bb[3] = b0[3];
                    bb[4] = b1[0]; bb[5] = b1[1]; bb[6] = b1[2]; bb[7] = b1[3];
                    acc2[ct] = __builtin_amdgcn_mfma_f32_16x16x32_bf16(a2[kit], bb, acc2[ct], 0, 0, 0);
                }
            __builtin_amdgcn_s_setprio(0);
        }
        {   // staging(ch): ssq partials + bf16 xsT + bf16 xsN[ch&1]
            unsigned short* xsNw = (unsigned short*)(smem + 17408 + 19456 * (ch & 1));
            const float* vf = (const float*)va;
            float pss[4] = {0.f, 0.f, 0.f, 0.f};
            #pragma unroll
            for (int j = 0; j < 8; ++j)
                #pragma unroll
                for (int i = 0; i < 4; ++i)
                    pss[i] = fmaf(vf[j * 4 + i], vf[j * 4 + i], pss[i]);
            float* rd2 = denom;              // overlay (denom dead here)
            #pragma unroll
            for (int i = 0; i < 4; ++i) rd2[(4 * pxg + i) * 17 + cg] = pss[i];

            #pragma unroll
            for (int i = 0; i < 4; ++i) {    // xsT: px-row, swizzled 16B block
                u32x4 t;
                #pragma unroll
                for (int jj = 0; jj < 4; ++jj)
                    t[jj] = cvtpk(vf[(2 * jj) * 4 + i], vf[(2 * jj + 1) * 4 + i]);
                *(u32x4*)&xsT[(4 * pxg + i) * 136 + pbT8] = t;
            }
            #pragma unroll
            for (int j = 0; j < 8; ++j) {    // xsN: c-row, 4 contiguous px
                u32x2 t2;
                t2[0] = cvtpk(vf[j * 4 + 0], vf[j * 4 + 1]);
                t2[1] = cvtpk(vf[j * 4 + 2], vf[j * 4 + 3]);
                *(u32x2*)&xsNw[(8 * cg + j) * 76 + 4 * pxg] = t2;
            }
        }
        bar_lds();                           // B1

        // ================= P2: invs (wave0) | GEMM1(ch) ====================
        if (tid < 64) {
            const float* rd2 = denom;
            float s = 0.f;
            #pragma unroll
            for (int g = 0; g < 16; ++g) s += rd2[tid * 17 + g];
            invs[tid] = 1.0f / fmaxf(sqrtf(s), EPS);
        }
        f4 acc1[4];
        #pragma unroll
        for (int t = 0; t < 4; ++t) acc1[t] = (f4){0.f, 0.f, 0.f, 0.f};
        __builtin_amdgcn_s_setprio(1);
        #pragma unroll
        for (int c0 = 0; c0 < 4; ++c0)
            #pragma unroll
            for (int pxt = 0; pxt < 4; ++pxt) {
                const int pb = (4 * c0 + q) ^ (4 * (pxt & 1) + l4);
                short8_t bf = *(const short8_t*)&xsT[(pxt * 16 + l15) * 136 + pb * 8];
                acc1[pxt] = __builtin_amdgcn_mfma_f32_16x16x32_bf16(af[c0], bf, acc1[pxt], 0, 0, 0);
            }
        __builtin_amdgcn_s_setprio(0);
        bar_lds();                           // B2 (xsT dead: saf takes over)

        // ================= P3: logits (NT), exp -> saf, denom ==============
        {
            const int p0 = pbase + ch * 64;
            float* lgp = logits + (size_t)n * K * P + p0;
            float bz[4];
            #pragma unroll
            for (int r = 0; r < 4; ++r) bz[r] = biass[16 * w + 4 * q + r];
            #pragma unroll
            for (int pxt = 0; pxt < 4; ++pxt) {
                const int pxl = pxt * 16 + l15;
                const float iv = invs[pxl];
                float psum = 0.f;
                #pragma unroll
                for (int r = 0; r < 4; ++r) {
                    const int k = 16 * w + 4 * q + r;
                    const float lv = acc1[pxt][r] * iv;
                    __builtin_nontemporal_store(lv, &lgp[(size_t)k * P + pxl]);
                    const float e = __expf(fmaf(lv, ALPHA, bz[r]));
                    saf[k * 68 + pxl] = e;
                    psum += e;
                }
                denom[(4 * w + q) * 68 + pxl] = psum;
            }
        }
        bar_lds();                           // B3

        // ================= P4: S + sa2 (shfl rfin) =========================
        {
            float dinv = 0.f;
            if (lane < 16) {
                const int pxr = 16 * w + lane;
                float dd = 0.f;
                #pragma unroll
                for (int g = 0; g < 16; ++g) dd += denom[g * 68 + pxr];
                dinv = 1.0f / dd;
            }
            const float* sp = &saf[lane * 68 + 16 * w];
            const float* ip = &invs[16 * w];
            float s = 0.f;
            unsigned pk[8];
            #pragma unroll
            for (int m = 0; m < 4; ++m) {
                f4 e  = *(const f4*)&sp[4 * m];
                f4 iv = *(const f4*)&ip[4 * m];
                const float r0 = __shfl(dinv, 4 * m + 0);
                const float r1 = __shfl(dinv, 4 * m + 1);
                const float r2 = __shfl(dinv, 4 * m + 2);
                const float r3 = __shfl(dinv, 4 * m + 3);
                s += e[0] * r0; s += e[1] * r1;
                s += e[2] * r2; s += e[3] * r3;
                const float v0 = e[0] * (r0 * iv[0]);
                const float v1 = e[1] * (r1 * iv[1]);
                const float v2 = e[2] * (r2 * iv[2]);
                const float v3 = e[3] * (r3 * iv[3]);
                pk[2 * m]     = cvtpk(v0, v1);
                pk[2 * m + 1] = cvtpk(v2, v3);
            }
            Sreg += s;
            *(u32x4*)&sa2s[lane * 72 + 16 * w]     = (u32x4){pk[0], pk[1], pk[2], pk[3]};
            *(u32x4*)&sa2s[lane * 72 + 16 * w + 8] = (u32x4){pk[4], pk[5], pk[6], pk[7]};
        }
        bar_lds();                           // B4 (sa2s visible for next P1)

        if (ch < 7) {
            #pragma unroll
            for (int j = 0; j < 8; ++j) va[j] = vb[j];
        }
    }

    // ---- drain GEMM2(7) ----
    {
        const unsigned short* xsNr = (const unsigned short*)(smem + 17408 + 19456 * 1);
        short8_t a2[2];
        #pragma unroll
        for (int kit = 0; kit < 2; ++kit)
            a2[kit] = *(const short8_t*)&sa2s[(16 * w + l15) * 72 + kit * 32 + 8 * q];
        __builtin_amdgcn_s_setprio(1);
        #pragma unroll
        for (int ct = 0; ct < 8; ++ct)
            #pragma unroll
            for (int kit = 0; kit < 2; ++kit) {
                const unsigned short* bp = &xsNr[(ct * 16 + l15) * 76 + kit * 32 + 8 * q];
                short4_t b0 = *(const short4_t*)bp;
                short4_t b1 = *(const short4_t*)(bp + 4);
                short8_t bb;
                bb[0] = b0[0]; bb[1] = b0[1]; bb[2] = b0[2]; bb[3] = b0[3];
                bb[4] = b1[0]; bb[5] = b1[1]; bb[6] = b1[2]; bb[7] = b1[3];
                acc2[ct] = __builtin_amdgcn_mfma_f32_16x16x32_bf16(a2[kit], bb, acc2[ct], 0, 0, 0);
            }
        __builtin_amdgcn_s_setprio(0);
    }

    // ---- epilogue: per-block partials (no atomics) ----
    float* vp = vlad_part + ((size_t)blk8 * N + n) * (size_t)(K * C);
    #pragma unroll
    for (int ct = 0; ct < 8; ++ct)
        #pragma unroll
        for (int r = 0; r < 4; ++r)
            vp[(16 * w + 4 * q + r) * C + ct * 16 + l15] = acc2[ct][r];

    red[tid] = Sreg;
    __syncthreads();
    if (tid < 64)
        Spart[((size_t)blk8 * N + n) * K + tid] =
            red[tid] + red[64 + tid] + red[128 + tid] + red[192 + tid];
}

// ---------------------------------------------------------------------------
// Post 1: reduce 8 partials, subtract W*S, intra-norm (c), write un-scaled
// rows; accumulate global-norm ss2 per n via one atomic per block.
// ---------------------------------------------------------------------------
__global__ __launch_bounds__(256) void k_post1(
    const float* __restrict__ vlad_part, const float* __restrict__ W,
    const float* __restrict__ Spart, float* __restrict__ out,
    float* __restrict__ ss2acc)
{
    __shared__ float red[16];
    const int tid = threadIdx.x;
    const int n  = blockIdx.x >> 2;
    const int kq = blockIdx.x & 3;
    const int kl = tid >> 4;           // 0..15
    const int ci = tid & 15;           // 0..15
    const int k  = kq * 16 + kl;
    const int c0 = ci * 8;

    float Sk = 0.f;
    #pragma unroll
    for (int ch = 0; ch < NCH2; ++ch) Sk += Spart[(size_t)(ch * N + n) * K + k];

    float v[8];
    #pragma unroll
    for (int l = 0; l < 8; ++l) v[l] = 0.f;
    #pragma unroll
    for (int ch = 0; ch < NCH2; ++ch) {
        const float* vp = vlad_part + ((size_t)(ch * N + n) * K + k) * C + c0;
        float4 a = *(const float4*)&vp[0];
        float4 b = *(const float4*)&vp[4];
        v[0] += a.x; v[1] += a.y; v[2] += a.z; v[3] += a.w;
        v[4] += b.x; v[5] += b.y; v[6] += b.z; v[7] += b.w;
    }

    float ss = 0.f;
    #pragma unroll
    for (int l = 0; l < 8; ++l) {
        float val = v[l] - W[(size_t)(c0 + l) * K + k] * Sk;
        v[l] = val;
        ss = fmaf(val, val, ss);
    }
    ss += __shfl_xor(ss, 1);
    ss += __shfl_xor(ss, 2);
    ss += __shfl_xor(ss, 4);
    ss += __shfl_xor(ss, 8);
    const float inv1 = 1.0f / fmaxf(sqrtf(ss), EPS);
    float ss2 = 0.f;
    #pragma unroll
    for (int l = 0; l < 8; ++l) { v[l] *= inv1; ss2 = fmaf(v[l], v[l], ss2); }
    ss2 += __shfl_xor(ss2, 1);
    ss2 += __shfl_xor(ss2, 2);
    ss2 += __shfl_xor(ss2, 4);
    ss2 += __shfl_xor(ss2, 8);
    if (ci == 0) red[kl] = ss2;
    __syncthreads();
    if (tid == 0) {
        float t = 0.f;
        #pragma unroll
        for (int i = 0; i < 16; ++i) t += red[i];
        atomicAdd(&ss2acc[n], t);
    }

    float* op = out + (size_t)n * K * C + (size_t)k * C + c0;
    *(float4*)&op[0] = (float4){v[0], v[1], v[2], v[3]};
    *(float4*)&op[4] = (float4){v[4], v[5], v[6], v[7]};
}

// ---------------------------------------------------------------------------
// Post 2: global L2 rescale in place. grid = N*4.
// ---------------------------------------------------------------------------
__global__ __launch_bounds__(256) void k_post2(
    float* __restrict__ out, const float* __restrict__ ss2acc)
{
    const int n   = blockIdx.x >> 2;
    const int seg = blockIdx.x & 3;
    const float inv2 = 1.0f / fmaxf(sqrtf(ss2acc[n]), EPS);
    float* p = out + (size_t)n * K * C + (size_t)seg * 2048 + (size_t)threadIdx.x * 8;
    float4 a = *(const float4*)&p[0];
    float4 b = *(const float4*)&p[4];
    a.x *= inv2; a.y *= inv2; a.z *= inv2; a.w *= inv2;
    b.x *= inv2; b.y *= inv2; b.z *= inv2; b.w *= inv2;
    *(float4*)&p[0] = a;
    *(float4*)&p[4] = b;
}

// ---------------------------------------------------------------------------
extern "C" void kernel_launch(void* const* d_in, const int* in_sizes, int n_in,
                              void* d_out, int out_size, void* d_ws, size_t ws_size,
                              hipStream_t stream)
{
    const float* x    = (const float*)d_in[0];
    const float* W    = (const float*)d_in[1];
    const float* bias = (const float*)d_in[2];

    float* out_vlad   = (float*)d_out;                       // N*K*C
    float* out_logits = (float*)d_out + (size_t)N * K * C;   // N*K*P

    float* ss2acc     = (float*)((char*)d_ws + 16384);                  // 256 B
    float* Spart      = (float*)((char*)d_ws + 32768);                  // 128 KiB
    float* vlad_part  = (float*)((char*)d_ws + 32768 + 131072);         // 16 MiB

    k_fused<<<dim3(N * NCH2), dim3(256), 0, stream>>>(
        x, W, bias, out_logits, vlad_part, Spart, ss2acc);
    k_post1<<<dim3(N * 4), dim3(256), 0, stream>>>(vlad_part, W, Spart, out_vlad, ss2acc);
    k_post2<<<dim3(N * 4), dim3(256), 0, stream>>>(out_vlad, ss2acc);
}